// Round 14
// baseline (4825.288 us; speedup 1.0000x reference)
//
#include <hip/hip_runtime.h>
#include <hip/hip_fp16.h>

#define B_ 512
#define T_ 256
#define H_ 1024
#define G4_ 4096
#define KL_ 20   // k-slices (of 32) resident in LDS
#define KR_ 8    // k-slices ki 20..27 (L2, compiler-scheduled reloads)
#define KS_ 4    // k-slices ki 28..31 (L2, streamed bursts)

typedef _Float16 half8 __attribute__((ext_vector_type(8)));
typedef float f32x4 __attribute__((ext_vector_type(4)));
typedef unsigned long long u64;

__device__ __forceinline__ float fast_sigmoid(float x) {
    return 1.0f / (1.0f + __expf(-x));
}
__device__ __forceinline__ float fast_tanh(float x) {
    float x2 = fminf(fmaxf(2.0f * x, -30.0f), 30.0f);
    float e = __expf(x2);
    return (e - 1.0f) / (e + 1.0f);
}

// L1-bypassing 16B load (two agent-scope b64 loads -> global_load_dwordx2 sc0).
// Used ONLY for h (the sole stale-able stream); lets us drop the per-step
// buffer_inv so read-only W lines stay warm in L1 across steps.
__device__ __forceinline__ half8 loadA(const _Float16* p) {
    union { half8 h; u64 q[2]; } v;
    const u64* q = (const u64*)p;
    v.q[0] = __hip_atomic_load(q,     __ATOMIC_RELAXED, __HIP_MEMORY_SCOPE_AGENT);
    v.q[1] = __hip_atomic_load(q + 1, __ATOMIC_RELAXED, __HIP_MEMORY_SCOPE_AGENT);
    return v.h;
}

// Repack W_hh [4096 x 1024] fp32 -> fp16 MFMA B-fragment order, split into
// W_lds (ki 0..19, per slot 81920 halves, read once at startup) and
// W_l2 (ki 20..31, per j-block 24576 halves; hot set 3 MB/XCD, proven fits).
__global__ void pack_w(const float* __restrict__ Whh,
                       _Float16* __restrict__ Wlds, _Float16* __restrict__ Wl2) {
    int idx = blockIdx.x * blockDim.x + threadIdx.x;   // over 4096*1024
    int gc = idx >> 10, k = idx & 1023;
    int nt = gc >> 10, u = gc & 1023;
    int jb = u >> 4, lk = u & 15;
    int ki = k >> 5, hi = (k >> 3) & 3, e = k & 7;
    int l = hi * 16 + lk;
    _Float16 v = (_Float16)Whh[idx];
    int frag = nt * 512 + l * 8 + e;
    if (ki < KL_) {
        int slot = jb >> 1, wj = jb & 1;
        Wlds[(size_t)slot * 81920 + wj * 40960 + ki * 2048 + frag] = v;
    } else {
        Wl2[(size_t)jb * 24576 + (ki - KL_) * 2048 + frag] = v;
    }
}

__global__ void init_misc(const float* __restrict__ bih, const float* __restrict__ bhh,
                          const float* __restrict__ bout,
                          float* __restrict__ bias, float* __restrict__ out) {
    int idx = blockIdx.x * blockDim.x + threadIdx.x;   // 131072 threads
    if (idx < G4_) bias[idx] = bih[idx] + bhh[idx];
    if (idx < B_ * T_) out[idx] = bout[0];
}

// Persistent kernel — r7's exact structure/schedule (best: 1787 us) with three
// changes only: (1) PLAIN launch + startup spin barrier (cooperative launch
// silently rejected 2 of 7 configs; plain is r12-proven), (2) h reads via
// L1-bypassing sc0 loads, (3) buffer_inv DELETED -> read-only W-L2 lines
// persist in L1 across steps (~96 KB footprint vs 32 KB L1, partial hits).
__global__ __launch_bounds__(512, 1)
void lstm_persist(const _Float16* __restrict__ Wlds,
                  const _Float16* __restrict__ Wl2,
                  const float* __restrict__ bias,
                  const float* __restrict__ x,
                  const float* __restrict__ Wih,
                  const float* __restrict__ Wout,
                  _Float16* __restrict__ hbuf,        // [8 xcd][2 phase][65536 halves]
                  float* __restrict__ out,
                  unsigned int* __restrict__ cnts) {  // [xcd] slot ctr, [8] startup,
                                                      // [16+xcd*32] barrier, [512+blk] slotmap
    extern __shared__ _Float16 Wl[];   // 81920 halves = 160 KB (full CU LDS)

    const int tid = threadIdx.x;
    unsigned int xcc;
    asm volatile("s_getreg_b32 %0, hwreg(HW_REG_XCC_ID)" : "=s"(xcc));
    const int xcd = (int)(xcc & 7u);
    if (tid == 0) {
        unsigned int s = __hip_atomic_fetch_add(&cnts[xcd], 1u,
                                                __ATOMIC_RELAXED, __HIP_MEMORY_SCOPE_AGENT);
        __hip_atomic_store(&cnts[512 + blockIdx.x], s,
                           __ATOMIC_RELAXED, __HIP_MEMORY_SCOPE_AGENT);
        __hip_atomic_fetch_add(&cnts[8], 1u, __ATOMIC_ACQ_REL, __HIP_MEMORY_SCOPE_AGENT);
        while (__hip_atomic_load(&cnts[8], __ATOMIC_ACQUIRE, __HIP_MEMORY_SCOPE_AGENT) < 256u)
            __builtin_amdgcn_s_sleep(2);
    }
    __syncthreads();
    const int slot = (int)__hip_atomic_load(&cnts[512 + blockIdx.x],
                                            __ATOMIC_RELAXED, __HIP_MEMORY_SCOPE_AGENT);
    const int nactive = (int)min(32u, __hip_atomic_load(&cnts[xcd], __ATOMIC_RELAXED,
                                                        __HIP_MEMORY_SCOPE_AGENT));
    if (slot >= 32) return;   // insurance only (1 WG/CU, 32 CUs/XCD)

    const int w = tid >> 6, l = tid & 63;
    const int lk = l & 15, hi = l >> 4;
    const int wr = w >> 1, wj = w & 1;        // 4 row-waves x 2 col-waves
    const int row0 = wr * 16;                 // local row base (0..48)
    const int u = slot * 32 + wj * 16 + lk;   // hidden unit for this lane

    // one-time: this slot's W ki 0..19 -> LDS (10240 half8)
    {
        const half8* src = (const half8*)(Wlds + (size_t)slot * 81920);
        half8* dst = (half8*)Wl;
#pragma unroll
        for (int o = 0; o < 20; ++o) dst[tid + o * 512] = src[tid + o * 512];
    }
    const _Float16* Bg = Wl2 + ((size_t)slot * 2 + wj) * 24576 + l * 8;
    // ki 20..27 B-fragments: loaded here; compiler rematerializes from L2/L1
    // inside the loop (r6-r9: pinning is unachievable at the 128-VGPR target).
    half8 breg[KR_ * 4];
#pragma unroll
    for (int kg = 0; kg < KR_; ++kg)
#pragma unroll
        for (int nt = 0; nt < 4; ++nt)
            breg[kg * 4 + nt] = *(const half8*)(Bg + kg * 2048 + nt * 512);
#pragma unroll
    for (int q = 0; q < KR_ * 4; ++q) asm volatile("" : "+v"(breg[q]));

    // one-time per-thread constants
    float bz[4], wi4[4];
#pragma unroll
    for (int nt = 0; nt < 4; ++nt) {
        int gc = nt * 1024 + u;
        bz[nt] = bias[gc];
        wi4[nt] = Wih[gc];
    }
    const float wout = Wout[u];
    int rowsl[4], rowsg[4];
#pragma unroll
    for (int r = 0; r < 4; ++r) {
        rowsl[r] = row0 + hi * 4 + r;
        rowsg[r] = xcd * 64 + rowsl[r];
    }
    const int kb = u >> 3, ue = u & 7;
    f32x4 creg = {0.f, 0.f, 0.f, 0.f};
    __syncthreads();

    _Float16* hx = hbuf + (size_t)xcd * 2 * 65536;
    const _Float16* Bgs = Bg + KR_ * 2048;   // streamed slices ki 28..31
    unsigned int* barp = &cnts[16 + xcd * 32];

    // x for t=0 preloaded; subsequent steps prefetch between arrive and wait
    float xv[4];
#pragma unroll
    for (int r = 0; r < 4; ++r) xv[r] = x[rowsg[r] * T_];

    for (int t = 0; t < T_; ++t) {
        // -------- wait phase (h(t-1) from all slots visible) --------
        if (t > 0) {
            if (tid == 0) {
                unsigned int tgt = (unsigned int)nactive * (unsigned int)t;
                while (__hip_atomic_load(barp, __ATOMIC_RELAXED, __HIP_MEMORY_SCOPE_AGENT) < tgt)
                    __builtin_amdgcn_s_sleep(2);
            }
            __syncthreads();
            // no buffer_inv: h reads below bypass L1 (sc0); all other streams
            // are read-only or L2-atomic, so L1 stays warm with W lines.
        }

        const int wb = t & 1, rb = wb ^ 1;
        f32x4 acc[4];
#pragma unroll
        for (int nt = 0; nt < 4; ++nt) {
#pragma unroll
            for (int r = 0; r < 4; ++r) acc[nt][r] = bz[nt] + xv[r] * wi4[nt];
        }

        if (t > 0) {
            const _Float16* Ap = hx + rb * 65536 + hi * 512 + (row0 + lk) * 8;
            // stream loads for ki 28,29 issue now; consumed at the very end
            half8 bs[8];
#pragma unroll
            for (int q = 0; q < 8; ++q)
                bs[q] = *(const half8*)(Bgs + (q >> 2) * 2048 + (q & 3) * 512);
            // LDS k-slices 0..9
#pragma unroll
            for (int ki = 0; ki < 10; ++ki) {
                half8 a = loadA(Ap + ki * 2048);
                const _Float16* bp = Wl + wj * 40960 + ki * 2048 + l * 8;
#pragma unroll
                for (int nt = 0; nt < 4; ++nt) {
                    half8 b = *(const half8*)(bp + nt * 512);
                    acc[nt] = __builtin_amdgcn_mfma_f32_16x16x32_f16(a, b, acc[nt], 0, 0, 0);
                }
            }
            // stream loads for ki 30,31
            half8 bs2[8];
#pragma unroll
            for (int q = 0; q < 8; ++q)
                bs2[q] = *(const half8*)(Bgs + (2 + (q >> 2)) * 2048 + (q & 3) * 512);
            // LDS k-slices 10..19
#pragma unroll
            for (int ki = 10; ki < KL_; ++ki) {
                half8 a = loadA(Ap + ki * 2048);
                const _Float16* bp = Wl + wj * 40960 + ki * 2048 + l * 8;
#pragma unroll
                for (int nt = 0; nt < 4; ++nt) {
                    half8 b = *(const half8*)(bp + nt * 512);
                    acc[nt] = __builtin_amdgcn_mfma_f32_16x16x32_f16(a, b, acc[nt], 0, 0, 0);
                }
            }
            // k-slices 20..27 (B via breg; compiler schedules L2/L1 reloads)
#pragma unroll
            for (int kg = 0; kg < KR_; ++kg) {
                half8 a = loadA(Ap + (KL_ + kg) * 2048);
#pragma unroll
                for (int nt = 0; nt < 4; ++nt)
                    acc[nt] = __builtin_amdgcn_mfma_f32_16x16x32_f16(a, breg[kg * 4 + nt], acc[nt], 0, 0, 0);
            }
            // streamed k-slices 28..31 (loads long in flight)
#pragma unroll
            for (int kg = 0; kg < 2; ++kg) {
                half8 a = loadA(Ap + (KL_ + KR_ + kg) * 2048);
#pragma unroll
                for (int nt = 0; nt < 4; ++nt)
                    acc[nt] = __builtin_amdgcn_mfma_f32_16x16x32_f16(a, bs[kg * 4 + nt], acc[nt], 0, 0, 0);
            }
#pragma unroll
            for (int kg = 0; kg < 2; ++kg) {
                half8 a = loadA(Ap + (KL_ + KR_ + 2 + kg) * 2048);
#pragma unroll
                for (int nt = 0; nt < 4; ++nt)
                    acc[nt] = __builtin_amdgcn_mfma_f32_16x16x32_f16(a, bs2[kg * 4 + nt], acc[nt], 0, 0, 0);
            }
        }

        // elementwise LSTM update; acc[0..3] = i,f,g,o
        _Float16* hn = hx + wb * 65536;
        float p4[4];
#pragma unroll
        for (int r = 0; r < 4; ++r) {
            float iv = fast_sigmoid(acc[0][r]);
            float fv = fast_sigmoid(acc[1][r]);
            float gv = fast_tanh(acc[2][r]);
            float ov = fast_sigmoid(acc[3][r]);
            float cv = fv * creg[r] + iv * gv;
            creg[r] = cv;
            float hv = ov * fast_tanh(cv);
            hn[(kb * 64 + rowsl[r]) * 8 + ue] = (_Float16)hv;
            p4[r] = hv * wout;
        }

        // -------- arrive phase: h stores drained by syncthreads, then signal --------
        if (t < T_ - 1) {
            __syncthreads();   // per-wave s_waitcnt vmcnt(0) precedes s_barrier
            if (tid == 0)
                __hip_atomic_fetch_add(barp, 1u, __ATOMIC_RELAXED, __HIP_MEMORY_SCOPE_AGENT);
        }

        // barrier-latency hiding: out projection + x prefetch for t+1
#pragma unroll
        for (int m = 1; m <= 8; m <<= 1) {
#pragma unroll
            for (int r = 0; r < 4; ++r) p4[r] += __shfl_xor(p4[r], m);
        }
        if (lk == 0) {
#pragma unroll
            for (int r = 0; r < 4; ++r)
                atomicAdd(&out[rowsg[r] * T_ + t], p4[r]);
        }
        if (t < T_ - 1) {
#pragma unroll
            for (int r = 0; r < 4; ++r) xv[r] = x[rowsg[r] * T_ + t + 1];
        }
    }
}

extern "C" void kernel_launch(void* const* d_in, const int* in_sizes, int n_in,
                              void* d_out, int out_size, void* d_ws, size_t ws_size,
                              hipStream_t stream) {
    const float* x    = (const float*)d_in[0];
    const float* Wih  = (const float*)d_in[1];
    const float* Whh  = (const float*)d_in[2];
    const float* bih  = (const float*)d_in[3];
    const float* bhh  = (const float*)d_in[4];
    const float* Wout = (const float*)d_in[5];
    const float* bout = (const float*)d_in[6];
    float* out = (float*)d_out;

    char* ws = (char*)d_ws;
    _Float16* Wlds = (_Float16*)ws;                        // 5 MB (32 x 160 KB)
    _Float16* Wl2  = (_Float16*)(ws + 5242880);            // 3 MB (64 x 48 KB)
    _Float16* hbuf = (_Float16*)(ws + (8 << 20));          // 2 MB (8 xcd x 2 x 128 KB)
    float* bias    = (float*)(ws + (10 << 20));            // 16 KB
    unsigned int* cnts = (unsigned int*)(ws + (10 << 20) + (64 << 10));  // 4 KB

    hipMemsetAsync(cnts, 0, 4096, stream);
    pack_w<<<(G4_ * H_) / 256, 256, 0, stream>>>(Whh, Wlds, Wl2);
    init_misc<<<512, 256, 0, stream>>>(bih, bhh, bout, bias, out);

    (void)hipFuncSetAttribute((const void*)lstm_persist,
                              hipFuncAttributeMaxDynamicSharedMemorySize, 163840);
    lstm_persist<<<dim3(256), dim3(512), 163840, stream>>>(
        Wlds, Wl2, bias, x, Wih, Wout, hbuf, out, cnts);
}

// Round 15
// 1761.097 us; speedup vs baseline: 2.7399x; 2.7399x over previous
//
#include <hip/hip_runtime.h>
#include <hip/hip_fp16.h>

#define B_ 512
#define T_ 256
#define H_ 1024
#define G4_ 4096
#define KL_ 20   // k-slices (of 32) resident in LDS
#define KR_ 8    // k-slices ki 20..27 (L2, compiler-scheduled reloads)
#define KS_ 4    // k-slices ki 28..31 (L2, streamed bursts)

typedef _Float16 half8 __attribute__((ext_vector_type(8)));
typedef float f32x4 __attribute__((ext_vector_type(4)));

__device__ __forceinline__ float fast_sigmoid(float x) {
    return 1.0f / (1.0f + __expf(-x));
}
__device__ __forceinline__ float fast_tanh(float x) {
    float x2 = fminf(fmaxf(2.0f * x, -30.0f), 30.0f);
    float e = __expf(x2);
    return (e - 1.0f) / (e + 1.0f);
}

// Repack W_hh [4096 x 1024] fp32 -> fp16 MFMA B-fragment order, split into
// W_lds (ki 0..19, per slot 81920 halves, read once at startup) and
// W_l2 (ki 20..31, per j-block 24576 halves; hot set 3 MB/XCD, proven fits).
__global__ void pack_w(const float* __restrict__ Whh,
                       _Float16* __restrict__ Wlds, _Float16* __restrict__ Wl2) {
    int idx = blockIdx.x * blockDim.x + threadIdx.x;   // over 4096*1024
    int gc = idx >> 10, k = idx & 1023;
    int nt = gc >> 10, u = gc & 1023;
    int jb = u >> 4, lk = u & 15;
    int ki = k >> 5, hi = (k >> 3) & 3, e = k & 7;
    int l = hi * 16 + lk;
    _Float16 v = (_Float16)Whh[idx];
    int frag = nt * 512 + l * 8 + e;
    if (ki < KL_) {
        int slot = jb >> 1, wj = jb & 1;
        Wlds[(size_t)slot * 81920 + wj * 40960 + ki * 2048 + frag] = v;
    } else {
        Wl2[(size_t)jb * 24576 + (ki - KL_) * 2048 + frag] = v;
    }
}

__global__ void init_misc(const float* __restrict__ bih, const float* __restrict__ bhh,
                          const float* __restrict__ bout,
                          float* __restrict__ bias, float* __restrict__ out) {
    int idx = blockIdx.x * blockDim.x + threadIdx.x;   // 131072 threads
    if (idx < G4_) bias[idx] = bih[idx] + bhh[idx];
    if (idx < B_ * T_) out[idx] = bout[0];
}

// Persistent kernel — round-7 measured-best structure (1787 us), byte-for-byte
// compute loop. Sole change: PLAIN launch + startup spin barrier replaces
// cooperative launch (which silently rejected 2 of 7 configs this session).
// 256 WGs x 512 thr, 1 WG/CU (160 KB LDS), grid == CU count -> all blocks
// co-resident, 32 per XCD by capacity. Batch across XCDs (zero cross-XCD
// traffic); 4x2 wave grid; W ki 0..19 LDS / ki 20..31 L2 (bs/bs2 issued early,
// consumed last); c in VGPRs; h double-buffered; split arrive/wait XCD
// barrier + L1 invalidate; out-projection + x prefetch in the tail.
__global__ __launch_bounds__(512, 1)
void lstm_persist(const _Float16* __restrict__ Wlds,
                  const _Float16* __restrict__ Wl2,
                  const float* __restrict__ bias,
                  const float* __restrict__ x,
                  const float* __restrict__ Wih,
                  const float* __restrict__ Wout,
                  _Float16* __restrict__ hbuf,        // [8 xcd][2 phase][65536 halves]
                  float* __restrict__ out,
                  unsigned int* __restrict__ cnts) {  // [xcd] slot ctr, [8] startup,
                                                      // [16+xcd*32] barrier, [512+blk] slotmap
    extern __shared__ _Float16 Wl[];   // 81920 halves = 160 KB (full CU LDS)

    const int tid = threadIdx.x;
    unsigned int xcc;
    asm volatile("s_getreg_b32 %0, hwreg(HW_REG_XCC_ID)" : "=s"(xcc));
    const int xcd = (int)(xcc & 7u);
    if (tid == 0) {
        unsigned int s = __hip_atomic_fetch_add(&cnts[xcd], 1u,
                                                __ATOMIC_RELAXED, __HIP_MEMORY_SCOPE_AGENT);
        __hip_atomic_store(&cnts[512 + blockIdx.x], s,
                           __ATOMIC_RELAXED, __HIP_MEMORY_SCOPE_AGENT);
        __hip_atomic_fetch_add(&cnts[8], 1u, __ATOMIC_ACQ_REL, __HIP_MEMORY_SCOPE_AGENT);
        while (__hip_atomic_load(&cnts[8], __ATOMIC_ACQUIRE, __HIP_MEMORY_SCOPE_AGENT) < 256u)
            __builtin_amdgcn_s_sleep(2);
    }
    __syncthreads();
    const int slot = (int)__hip_atomic_load(&cnts[512 + blockIdx.x],
                                            __ATOMIC_RELAXED, __HIP_MEMORY_SCOPE_AGENT);
    const int nactive = (int)min(32u, __hip_atomic_load(&cnts[xcd], __ATOMIC_RELAXED,
                                                        __HIP_MEMORY_SCOPE_AGENT));
    if (slot >= 32) return;   // insurance only (1 WG/CU, 32 CUs/XCD)

    const int w = tid >> 6, l = tid & 63;
    const int lk = l & 15, hi = l >> 4;
    const int wr = w >> 1, wj = w & 1;        // 4 row-waves x 2 col-waves
    const int row0 = wr * 16;                 // local row base (0..48)
    const int u = slot * 32 + wj * 16 + lk;   // hidden unit for this lane

    // one-time: this slot's W ki 0..19 -> LDS (10240 half8)
    {
        const half8* src = (const half8*)(Wlds + (size_t)slot * 81920);
        half8* dst = (half8*)Wl;
#pragma unroll
        for (int o = 0; o < 20; ++o) dst[tid + o * 512] = src[tid + o * 512];
    }
    const _Float16* Bg = Wl2 + ((size_t)slot * 2 + wj) * 24576 + l * 8;
    // ki 20..27 B-fragments (as in r7; compiler reloads from warm L2/L1)
    half8 breg[KR_ * 4];
#pragma unroll
    for (int kg = 0; kg < KR_; ++kg)
#pragma unroll
        for (int nt = 0; nt < 4; ++nt)
            breg[kg * 4 + nt] = *(const half8*)(Bg + kg * 2048 + nt * 512);
#pragma unroll
    for (int q = 0; q < KR_ * 4; ++q) asm volatile("" : "+v"(breg[q]));

    // one-time per-thread constants
    float bz[4], wi4[4];
#pragma unroll
    for (int nt = 0; nt < 4; ++nt) {
        int gc = nt * 1024 + u;
        bz[nt] = bias[gc];
        wi4[nt] = Wih[gc];
    }
    const float wout = Wout[u];
    int rowsl[4], rowsg[4];
#pragma unroll
    for (int r = 0; r < 4; ++r) {
        rowsl[r] = row0 + hi * 4 + r;
        rowsg[r] = xcd * 64 + rowsl[r];
    }
    const int kb = u >> 3, ue = u & 7;
    f32x4 creg = {0.f, 0.f, 0.f, 0.f};
    __syncthreads();

    _Float16* hx = hbuf + (size_t)xcd * 2 * 65536;
    const _Float16* Bgs = Bg + KR_ * 2048;   // streamed slices ki 28..31
    unsigned int* barp = &cnts[16 + xcd * 32];

    // x for t=0 preloaded; subsequent steps prefetch between arrive and wait
    float xv[4];
#pragma unroll
    for (int r = 0; r < 4; ++r) xv[r] = x[rowsg[r] * T_];

    for (int t = 0; t < T_; ++t) {
        // -------- wait phase (h(t-1) from all slots visible) --------
        if (t > 0) {
            if (tid == 0) {
                unsigned int tgt = (unsigned int)nactive * (unsigned int)t;
                while (__hip_atomic_load(barp, __ATOMIC_RELAXED, __HIP_MEMORY_SCOPE_AGENT) < tgt)
                    __builtin_amdgcn_s_sleep(2);
            }
            __syncthreads();
            asm volatile("buffer_inv sc0" ::: "memory");   // drop stale L1 lines
        }

        const int wb = t & 1, rb = wb ^ 1;
        f32x4 acc[4];
#pragma unroll
        for (int nt = 0; nt < 4; ++nt) {
#pragma unroll
            for (int r = 0; r < 4; ++r) acc[nt][r] = bz[nt] + xv[r] * wi4[nt];
        }

        if (t > 0) {
            const _Float16* Ap = hx + rb * 65536 + hi * 512 + (row0 + lk) * 8;
            // stream loads for ki 28,29 issue now; consumed at the very end
            half8 bs[8];
#pragma unroll
            for (int q = 0; q < 8; ++q)
                bs[q] = *(const half8*)(Bgs + (q >> 2) * 2048 + (q & 3) * 512);
            // LDS k-slices 0..9
#pragma unroll
            for (int ki = 0; ki < 10; ++ki) {
                half8 a = *(const half8*)(Ap + ki * 2048);
                const _Float16* bp = Wl + wj * 40960 + ki * 2048 + l * 8;
#pragma unroll
                for (int nt = 0; nt < 4; ++nt) {
                    half8 b = *(const half8*)(bp + nt * 512);
                    acc[nt] = __builtin_amdgcn_mfma_f32_16x16x32_f16(a, b, acc[nt], 0, 0, 0);
                }
            }
            // stream loads for ki 30,31
            half8 bs2[8];
#pragma unroll
            for (int q = 0; q < 8; ++q)
                bs2[q] = *(const half8*)(Bgs + (2 + (q >> 2)) * 2048 + (q & 3) * 512);
            // LDS k-slices 10..19
#pragma unroll
            for (int ki = 10; ki < KL_; ++ki) {
                half8 a = *(const half8*)(Ap + ki * 2048);
                const _Float16* bp = Wl + wj * 40960 + ki * 2048 + l * 8;
#pragma unroll
                for (int nt = 0; nt < 4; ++nt) {
                    half8 b = *(const half8*)(bp + nt * 512);
                    acc[nt] = __builtin_amdgcn_mfma_f32_16x16x32_f16(a, b, acc[nt], 0, 0, 0);
                }
            }
            // k-slices 20..27 (B via breg / warm-L2 reloads)
#pragma unroll
            for (int kg = 0; kg < KR_; ++kg) {
                half8 a = *(const half8*)(Ap + (KL_ + kg) * 2048);
#pragma unroll
                for (int nt = 0; nt < 4; ++nt)
                    acc[nt] = __builtin_amdgcn_mfma_f32_16x16x32_f16(a, breg[kg * 4 + nt], acc[nt], 0, 0, 0);
            }
            // streamed k-slices 28..31 (loads long in flight)
#pragma unroll
            for (int kg = 0; kg < 2; ++kg) {
                half8 a = *(const half8*)(Ap + (KL_ + KR_ + kg) * 2048);
#pragma unroll
                for (int nt = 0; nt < 4; ++nt)
                    acc[nt] = __builtin_amdgcn_mfma_f32_16x16x32_f16(a, bs[kg * 4 + nt], acc[nt], 0, 0, 0);
            }
#pragma unroll
            for (int kg = 0; kg < 2; ++kg) {
                half8 a = *(const half8*)(Ap + (KL_ + KR_ + 2 + kg) * 2048);
#pragma unroll
                for (int nt = 0; nt < 4; ++nt)
                    acc[nt] = __builtin_amdgcn_mfma_f32_16x16x32_f16(a, bs2[kg * 4 + nt], acc[nt], 0, 0, 0);
            }
        }

        // elementwise LSTM update; acc[0..3] = i,f,g,o
        _Float16* hn = hx + wb * 65536;
        float p4[4];
#pragma unroll
        for (int r = 0; r < 4; ++r) {
            float iv = fast_sigmoid(acc[0][r]);
            float fv = fast_sigmoid(acc[1][r]);
            float gv = fast_tanh(acc[2][r]);
            float ov = fast_sigmoid(acc[3][r]);
            float cv = fv * creg[r] + iv * gv;
            creg[r] = cv;
            float hv = ov * fast_tanh(cv);
            hn[(kb * 64 + rowsl[r]) * 8 + ue] = (_Float16)hv;
            p4[r] = hv * wout;
        }

        // -------- arrive phase: h stores drained by syncthreads, then signal --------
        if (t < T_ - 1) {
            __syncthreads();   // per-wave s_waitcnt vmcnt(0) precedes s_barrier
            if (tid == 0)
                __hip_atomic_fetch_add(barp, 1u, __ATOMIC_RELAXED, __HIP_MEMORY_SCOPE_AGENT);
        }

        // barrier-latency hiding: out projection + x prefetch for t+1
#pragma unroll
        for (int m = 1; m <= 8; m <<= 1) {
#pragma unroll
            for (int r = 0; r < 4; ++r) p4[r] += __shfl_xor(p4[r], m);
        }
        if (lk == 0) {
#pragma unroll
            for (int r = 0; r < 4; ++r)
                atomicAdd(&out[rowsg[r] * T_ + t], p4[r]);
        }
        if (t < T_ - 1) {
#pragma unroll
            for (int r = 0; r < 4; ++r) xv[r] = x[rowsg[r] * T_ + t + 1];
        }
    }
}

extern "C" void kernel_launch(void* const* d_in, const int* in_sizes, int n_in,
                              void* d_out, int out_size, void* d_ws, size_t ws_size,
                              hipStream_t stream) {
    const float* x    = (const float*)d_in[0];
    const float* Wih  = (const float*)d_in[1];
    const float* Whh  = (const float*)d_in[2];
    const float* bih  = (const float*)d_in[3];
    const float* bhh  = (const float*)d_in[4];
    const float* Wout = (const float*)d_in[5];
    const float* bout = (const float*)d_in[6];
    float* out = (float*)d_out;

    char* ws = (char*)d_ws;
    _Float16* Wlds = (_Float16*)ws;                        // 5 MB (32 x 160 KB)
    _Float16* Wl2  = (_Float16*)(ws + 5242880);            // 3 MB (64 x 48 KB)
    _Float16* hbuf = (_Float16*)(ws + (8 << 20));          // 2 MB (8 xcd x 2 x 128 KB)
    float* bias    = (float*)(ws + (10 << 20));            // 16 KB
    unsigned int* cnts = (unsigned int*)(ws + (10 << 20) + (64 << 10));  // 4 KB

    hipMemsetAsync(cnts, 0, 4096, stream);
    pack_w<<<(G4_ * H_) / 256, 256, 0, stream>>>(Whh, Wlds, Wl2);
    init_misc<<<512, 256, 0, stream>>>(bih, bhh, bout, bias, out);

    (void)hipFuncSetAttribute((const void*)lstm_persist,
                              hipFuncAttributeMaxDynamicSharedMemorySize, 163840);
    lstm_persist<<<dim3(256), dim3(512), 163840, stream>>>(
        Wlds, Wl2, bias, x, Wih, Wout, hbuf, out, cnts);
}